// Round 7
// baseline (486.487 us; speedup 1.0000x reference)
//
#include <hip/hip_runtime.h>

// ---- filter / neuron constants (double, matching the Python reference) ----
#define EMD 0.8824969025845955      // exp(-1/8)
#define ESD 0.6065306597126334      // exp(-1/2)
#define A1C ((float)(EMD + ESD))                    // y[t-1] coeff
#define A2C ((float)(-(EMD * ESD)))                 // y[t-2] coeff
#define BC  ((float)((8.0 / 6.0) * (EMD - ESD)))    // x[t] coeff (ETA=8/6)
#define EMF ((float)EMD)                            // reset decay

// B=64, T=300. Layers: 300 -> 500 -> 200 -> 500 -> 300.
//
// Exactness contract (absmax 0.0 through r11): reference currents are a
// SEQUENTIAL ascending-i fp32 fold of W[o,i]*s[i]; spikes are exactly 0/1.
// Skipping s==0 terms is bitwise-neutral; set bits processed ascending is
// the SAME add sequence. Spikes travel as packed u32 masks (bit j of word w
// = neuron w*32+j); walk = ascending bits within (32- or 64-bit) word,
// words/chunks ascending -> identical fold per (t,o).
//
// History: r6 (VALU bit-extract) 105->131us: >1 VALU op per accumulated
// float loses. r7 (dense reg-weight fmac) 8x: VGPR spill. r8 (16KB LDS +
// reg staging + prefetch) 77us. r9 (masks via s_load) 81.5us: SMEM shares
// lgkmcnt with DS out-of-order. r10 (global_load_lds; lif4_tr fusion into
// 1-wave/CU scan) regressed both. r11 (r8 staging + vmcnt mask loads +
// prefetch-16 scans) 475us total, spmm 80us. r12: L1/L3 go OPL=4 (4 o/lane,
// ds_read_b128 -> wave-visits halve, exposure halves, LDS-pipe time same);
// L2/L4 go KG=64 (64-bit words -> chunk iters and word boundaries halve);
// lif4 outputs to ws + one fused output transpose.

// ---------------------------------------------------------------------------
// Fused weight transposes: z selects one of 4 W[O,K] -> Wt[K,O] jobs.
// ---------------------------------------------------------------------------
__global__ __launch_bounds__(256) void transpose_w4(
    const float* __restrict__ W1, float* __restrict__ D1,
    const float* __restrict__ W2, float* __restrict__ D2,
    const float* __restrict__ W3, float* __restrict__ D3,
    const float* __restrict__ W4, float* __restrict__ D4)
{
    __shared__ float tile[32][33];
    int R, C; const float* S; float* D;
    switch (blockIdx.z) {
        case 0:  S = W1; D = D1; R = 500; C = 300; break;
        case 1:  S = W2; D = D2; R = 200; C = 500; break;
        case 2:  S = W3; D = D3; R = 500; C = 200; break;
        default: S = W4; D = D4; R = 300; C = 500; break;
    }
    const int c0 = blockIdx.x * 32;
    const int r0 = blockIdx.y * 32;
    if (c0 >= C || r0 >= R) return;       // block-uniform, before barrier
    const int tx = threadIdx.x;           // 0..31
    const int ty = threadIdx.y;           // 0..7
#pragma unroll
    for (int s = 0; s < 4; s++) {
        const int r = r0 + ty + 8 * s;
        const int c = c0 + tx;
        if (r < R && c < C) tile[ty + 8 * s][tx] = S[(size_t)r * C + c];
    }
    __syncthreads();
#pragma unroll
    for (int s = 0; s < 4; s++) {
        const int c = c0 + ty + 8 * s;
        const int r = r0 + tx;
        if (c < C && r < R) D[(size_t)c * R + r] = tile[tx][ty + 8 * s];
    }
}

// ---------------------------------------------------------------------------
// Input transpose+pack: src [B][R=K][C=T] binary floats -> masks
// M[b][t][kw] (MW u32 per row), bit j of word kw = (src[b][kw*32+j][t] != 0).
// ---------------------------------------------------------------------------
__global__ __launch_bounds__(256) void transpose_pack(
    const float* __restrict__ src, unsigned* __restrict__ M,
    int R, int C, int MW)
{
    __shared__ float tile[32][33];
    const int c0 = blockIdx.x * 32;       // t block
    const int r0 = blockIdx.y * 32;       // k block (one mask word)
    const int b  = blockIdx.z;
    const float* S = src + (size_t)b * R * C;
    const int tx = threadIdx.x;           // 0..31
    const int ty = threadIdx.y;           // 0..7
#pragma unroll
    for (int s = 0; s < 4; s++) {
        const int r = r0 + ty + 8 * s;
        const int c = c0 + tx;
        tile[ty + 8 * s][tx] = (r < R && c < C) ? S[(size_t)r * C + c] : 0.0f;
    }
    __syncthreads();
    const int wv   = ty >> 1;             // 0..3
    const int half = ty & 1;
#pragma unroll
    for (int s = 0; s < 4; s++) {
        const int tl = wv * 8 + s * 2 + half;          // 0..31, both halves
        const float v = tile[tx][tl];                  // OOB pre-zeroed
        const unsigned long long mb = __ballot(v != 0.0f);
        const int t = c0 + tl;
        if (tx == 0 && t < C) {
            const unsigned w32 = half ? (unsigned)(mb >> 32) : (unsigned)mb;
            M[((size_t)b * C + t) * MW + (r0 >> 5)] = w32;
        }
    }
}

// ---------------------------------------------------------------------------
// Sparse spike GEMM, templated:
//   OPL = outputs per lane (2 -> float2/ds_read_b64, 4 -> float4/b128)
//   KGT = K-chunk rows (32 -> u32 mask words, 64 -> u64 words)
// C[b,t,o] = sum_i Wt[i,o] * bit(M[b,t,i]), skipping zeros.
// Block: 256 thr (4 waves), o-chunk OCN=64*OPL, t-chunk 32 (8 t/wave).
// K staged in KGT-row LDS chunks (32 KB both configs), weights register-
// prefetched one chunk ahead (r8 staging). Masks: per-lane-addressed VECTOR
// broadcast loads (vmcnt, not s_load/lgkmcnt); readfirstlane at walk time.
// Walk: scalar ctz on wave-uniform words, 4/2/1-wide groups, OPL adds per
// set-bit visit.
//   L1/L3 (O=500): OPL=4, KGT=32 -> wave-visits halve vs r11 (2 o-blocks).
//   L2/L4 (K=500, sparse): OPL=2, KGT=64 -> chunk iters + word bounds halve.
// ---------------------------------------------------------------------------
#define TCN 32

template<int OPL> struct VecSel;
template<> struct VecSel<2> { using T = float2; };
template<> struct VecSel<4> { using T = float4; };

__device__ __forceinline__ void vzero(float2& a){ a.x=0.f; a.y=0.f; }
__device__ __forceinline__ void vzero(float4& a){ a.x=0.f; a.y=0.f; a.z=0.f; a.w=0.f; }
__device__ __forceinline__ void vaccum(float2& a, const float2 w){ a.x+=w.x; a.y+=w.y; }
__device__ __forceinline__ void vaccum(float4& a, const float4 w){ a.x+=w.x; a.y+=w.y; a.z+=w.z; a.w+=w.w; }

__device__ __forceinline__ unsigned long long rfl64(unsigned long long v){
    const unsigned lo = __builtin_amdgcn_readfirstlane((unsigned)v);
    const unsigned hi = __builtin_amdgcn_readfirstlane((unsigned)(v >> 32));
    return (((unsigned long long)hi) << 32) | lo;
}

// walk one wave-uniform mask word into one OPL-wide accumulator (ascending j)
#define WALK(mw, accu, wl)                                                    \
    {                                                                         \
        unsigned long long mask_ = (mw);                                      \
        int n_ = __popcll(mask_);                                             \
        while (n_ >= 4) {                                                     \
            const int j0_ = (int)__builtin_ctzll(mask_); mask_ &= mask_-1ull; \
            const int j1_ = (int)__builtin_ctzll(mask_); mask_ &= mask_-1ull; \
            const int j2_ = (int)__builtin_ctzll(mask_); mask_ &= mask_-1ull; \
            const int j3_ = (int)__builtin_ctzll(mask_); mask_ &= mask_-1ull; \
            const VT w0_ = *(const VT*)(&(wl)[j0_ * OCN]);                    \
            const VT w1_ = *(const VT*)(&(wl)[j1_ * OCN]);                    \
            const VT w2_ = *(const VT*)(&(wl)[j2_ * OCN]);                    \
            const VT w3_ = *(const VT*)(&(wl)[j3_ * OCN]);                    \
            vaccum(accu, w0_); vaccum(accu, w1_);                             \
            vaccum(accu, w2_); vaccum(accu, w3_);                             \
            n_ -= 4;                                                          \
        }                                                                     \
        if (n_ >= 2) {                                                        \
            const int j0_ = (int)__builtin_ctzll(mask_); mask_ &= mask_-1ull; \
            const int j1_ = (int)__builtin_ctzll(mask_); mask_ &= mask_-1ull; \
            const VT w0_ = *(const VT*)(&(wl)[j0_ * OCN]);                    \
            const VT w1_ = *(const VT*)(&(wl)[j1_ * OCN]);                    \
            vaccum(accu, w0_); vaccum(accu, w1_);                             \
            n_ -= 2;                                                          \
        }                                                                     \
        if (n_ > 0) {                                                         \
            const int j0_ = (int)__builtin_ctzll(mask_);                      \
            const VT w0_ = *(const VT*)(&(wl)[j0_ * OCN]);                    \
            vaccum(accu, w0_);                                                \
        }                                                                     \
    }

template<int OPL, int KGT>
__global__ __launch_bounds__(256) void spmm_snn(
    const unsigned* __restrict__ M, const float* __restrict__ Wt,
    float* __restrict__ C, int K, int O, int T, int MW)
{
    constexpr int OCN = OPL * 64;
    using VT = typename VecSel<OPL>::T;
    __shared__ float Wls[KGT * OCN];      // 32 KB for both configs
    const int tid  = threadIdx.x;
    const int lane = tid & 63;
    const int wv   = tid >> 6;            // 0..3 (per-lane -> vector loads)
    const int oc   = blockIdx.x * OCN;
    const int t0   = blockIdx.y * TCN;
    const int b    = blockIdx.z;

    const unsigned* Mb = M + (size_t)b * T * MW;
    float* Cb = C + (size_t)b * T * O;

    // staging: KGT x OCN floats = 2048 float4 = 256 thr x 8
    constexpr int C4 = OCN / 4;           // float4 columns per row
    VT acc[8];
#pragma unroll
    for (int u = 0; u < 8; u++) vzero(acc[u]);

    const int nkc = (K + KGT - 1) / KGT;
    float4 wpf[8];

#define LOADW(kc)                                                              \
    {                                                                          \
        const int kb_ = (kc) * KGT;                                            \
        _Pragma("unroll")                                                      \
        for (int r = 0; r < 8; r++) {                                          \
            const int idx = r * 256 + tid;                                     \
            const int k = kb_ + idx / C4;                                      \
            const int o = oc + (idx % C4) * 4;                                 \
            float4 w = make_float4(0.f, 0.f, 0.f, 0.f);                        \
            if (k < K && o + 3 < O)                                            \
                w = *reinterpret_cast<const float4*>(&Wt[(size_t)k * O + o]);  \
            wpf[r] = w;                                                        \
        }                                                                      \
    }

#define STOREW()                                                               \
    {                                                                          \
        _Pragma("unroll")                                                      \
        for (int r = 0; r < 8; r++) {                                          \
            const int idx = r * 256 + tid;                                     \
            *reinterpret_cast<float4*>(                                        \
                &Wls[(idx / C4) * OCN + (idx % C4) * 4]) = wpf[r];             \
        }                                                                      \
    }

    // mask rows: per-lane (tid-derived) addresses -> VECTOR broadcast loads
    // on vmcnt. readfirstlane only at walk time. Invalid-t addresses clamp
    // to row 0 and the value is masked to 0.
    const unsigned* mrow[8];
    bool tvalid[8];
#pragma unroll
    for (int u = 0; u < 8; u++) {
        const int t = t0 + u * 4 + wv;
        tvalid[u] = (t < T);
        mrow[u] = Mb + (size_t)(tvalid[u] ? t : 0) * MW;
    }

    unsigned long long mk[8], mkn[8];
#define LOADM(kc, dst)                                                         \
    {                                                                          \
        _Pragma("unroll")                                                      \
        for (int u = 0; u < 8; u++) {                                          \
            unsigned long long v_;                                             \
            if constexpr (KGT == 64)                                           \
                v_ = ((const unsigned long long*)mrow[u])[(kc)];               \
            else                                                               \
                v_ = (unsigned long long)mrow[u][(kc)];                        \
            dst[u] = tvalid[u] ? v_ : 0ull;                                    \
        }                                                                      \
    }

    LOADW(0)
    LOADM(0, mk)
    STOREW()
    __syncthreads();

    // per-lane LDS base: row j's VT for this lane at float offset j*OCN
    const float* wl = &Wls[lane * OPL];

    for (int kc = 0; kc < nkc; kc++) {
        if (kc + 1 < nkc) {
            LOADW(kc + 1)          // global->reg, lands during the walk
            LOADM(kc + 1, mkn)
        }

#pragma unroll
        for (int u = 0; u < 8; u++) {
            const unsigned long long m_ = rfl64(mk[u]);
            WALK(m_, acc[u], wl)               // t = t0 + u*4 + wv
        }

        if (kc + 1 < nkc) {
            __syncthreads();       // all waves done reading Wls
            STOREW()
#pragma unroll
            for (int u = 0; u < 8; u++) mk[u] = mkn[u];
            __syncthreads();       // Wls chunk kc+1 visible
        }
    }

#pragma unroll
    for (int u = 0; u < 8; u++) {
        const int t = t0 + u * 4 + wv;
        const int o = oc + lane * OPL;
        if (t < T && o + OPL - 1 < O)         // O mult of OPL -> all-or-nothing
            *reinterpret_cast<VT*>(&Cb[(size_t)t * O + o]) = acc[u];
    }
#undef LOADW
#undef STOREW
#undef LOADM
}

// ---------------------------------------------------------------------------
// LIF (layers 1-3): currents C[b,t,o] -> packed spike masks M[b][t][MW].
// One wave per (b, 64-o-chunk); per t: LIF step + __ballot -> one 8B store.
// Prefetch ring depth 16: ~1 wave/SIMD, ILP is the only latency cover.
// ---------------------------------------------------------------------------
#define LIF_STEP_S(xval, sval)                                                 \
    {                                                                          \
        const float y = A1 * y1 + A2 * y2 + Bc * (xval); y2 = y1; y1 = y;      \
        const float v = y + bi + r;                                            \
        sval = (v >= 1.0f) ? 1.0f : 0.0f;                                      \
        r = r * EMF - sval;                                                    \
    }

__global__ __launch_bounds__(64) void lif_pack(
    const float* __restrict__ C, unsigned* __restrict__ M,
    const float* __restrict__ bias,
    const float* __restrict__ a1p, const float* __restrict__ a2p,
    const float* __restrict__ bp, int O, int MW)
{
    const int lane = threadIdx.x;
    const int o = blockIdx.x * 64 + lane;
    const int b = blockIdx.y;
    if (o >= O) return;                    // exited lanes ballot as 0
    const float A1 = a1p[0], A2 = a2p[0], Bc = bp[0];
    const float bi = bias[o];
    const float* col = C + (size_t)b * 300 * O + o;
    unsigned long long* Mp =
        (unsigned long long*)(M + (size_t)b * 300 * MW);
    const int pair = blockIdx.x;
    const int hw   = MW >> 1;

    float pf[16];
#pragma unroll
    for (int u = 0; u < 16; u++) pf[u] = col[(size_t)u * O];

    float y1 = 0.f, y2 = 0.f, r = 0.f;
    for (int blk = 0; blk < 18; blk++) {       // t = 0..287
#pragma unroll
        for (int u = 0; u < 16; u++) {
            const int t = blk * 16 + u;
            const float x = pf[u];
            if (t + 16 < 300) pf[u] = col[(size_t)(t + 16) * O];
            float s;
            LIF_STEP_S(x, s)
            const unsigned long long mb = __ballot(s != 0.0f);
            if (lane == 0) Mp[(size_t)t * hw + pair] = mb;
        }
    }
#pragma unroll
    for (int u = 0; u < 12; u++) {             // t = 288..299
        const float x = pf[u];
        float s;
        LIF_STEP_S(x, s)
        const unsigned long long mb = __ballot(s != 0.0f);
        if (lane == 0) Mp[(size_t)(288 + u) * hw + pair] = mb;
    }
}

// ---------------------------------------------------------------------------
// Layer-4 LIF + fixed output dual-exp IIR. Cc: currents (read-only),
// S4: spikes out, F: filtered out, all [B,T,300]. Prefetch ring depth 16.
// ---------------------------------------------------------------------------
__global__ __launch_bounds__(64) void lif4_t(
    const float* __restrict__ Cc, float* __restrict__ S4,
    float* __restrict__ F, const float* __restrict__ bias,
    const float* __restrict__ a1p, const float* __restrict__ a2p,
    const float* __restrict__ bp, int O)
{
    const int o = blockIdx.x * 64 + threadIdx.x;
    const int b = blockIdx.y;
    if (o >= O) return;
    const float A1 = a1p[0], A2 = a2p[0], Bc = bp[0];
    const float bi = bias[o];
    const float* col = Cc + (size_t)b * 300 * O + o;
    float* scol = S4 + (size_t)b * 300 * O + o;
    float* fcol = F  + (size_t)b * 300 * O + o;

    float pf[16];
#pragma unroll
    for (int u = 0; u < 16; u++) pf[u] = col[(size_t)u * O];

    float y1 = 0.f, y2 = 0.f, r = 0.f;
    float z1 = 0.f, z2 = 0.f;
    for (int blk = 0; blk < 18; blk++) {       // t = 0..287
#pragma unroll
        for (int u = 0; u < 16; u++) {
            const int t = blk * 16 + u;
            const float x = pf[u];
            if (t + 16 < 300) pf[u] = col[(size_t)(t + 16) * O];
            float s;
            LIF_STEP_S(x, s)
            const float z = A1C * z1 + A2C * z2 + BC * s; z2 = z1; z1 = z;
            scol[(size_t)t * O] = s;
            fcol[(size_t)t * O] = z;
        }
    }
#pragma unroll
    for (int u = 0; u < 12; u++) {             // t = 288..299
        const int t = 288 + u;
        const float x = pf[u];
        float s;
        LIF_STEP_S(x, s)
        const float z = A1C * z1 + A2C * z2 + BC * s; z2 = z1; z1 = z;
        scol[(size_t)t * O] = s;
        fcol[(size_t)t * O] = z;
    }
}

// ---------------------------------------------------------------------------
// Fused final transposes: z<64 -> s4 [b][300][300]^T, z>=64 -> filt. Both
// jobs read independent ws buffers and write independent d_out regions, so
// they run concurrently in one launch.
// ---------------------------------------------------------------------------
__global__ __launch_bounds__(256) void transpose_out2(
    const float* __restrict__ s4, const float* __restrict__ flt,
    float* __restrict__ o1, float* __restrict__ o2)
{
    __shared__ float tile[32][33];
    const int z   = blockIdx.z;
    const int b   = z & 63;
    const int job = z >> 6;
    const float* S = (job ? flt : s4) + (size_t)b * 90000;
    float* D = (job ? o2 : o1) + (size_t)b * 90000;
    const int c0 = blockIdx.x * 32;
    const int r0 = blockIdx.y * 32;
    const int tx = threadIdx.x;
    const int ty = threadIdx.y;
#pragma unroll
    for (int s = 0; s < 4; s++) {
        const int r = r0 + ty + 8 * s;
        const int c = c0 + tx;
        if (r < 300 && c < 300) tile[ty + 8 * s][tx] = S[(size_t)r * 300 + c];
    }
    __syncthreads();
#pragma unroll
    for (int s = 0; s < 4; s++) {
        const int c = c0 + ty + 8 * s;
        const int r = r0 + tx;
        if (c < 300 && r < 300) D[(size_t)c * 300 + r] = tile[tx][ty + 8 * s];
    }
}

// ---------------------------------------------------------------------------
extern "C" void kernel_launch(void* const* d_in, const int* in_sizes, int n_in,
                              void* d_out, int out_size, void* d_ws, size_t ws_size,
                              hipStream_t stream)
{
    const float* inputs = (const float*)d_in[0];           // [64,300,300] binary
    const float* a1_1 = (const float*)d_in[1];
    const float* a2_1 = (const float*)d_in[2];
    const float* b_1  = (const float*)d_in[3];
    const float* W1   = (const float*)d_in[4];             // [500,300]
    const float* bias1= (const float*)d_in[5];
    const float* a1_2 = (const float*)d_in[6];
    const float* a2_2 = (const float*)d_in[7];
    const float* b_2  = (const float*)d_in[8];
    const float* W2   = (const float*)d_in[9];             // [200,500]
    const float* bias2= (const float*)d_in[10];
    const float* a1_3 = (const float*)d_in[11];
    const float* a2_3 = (const float*)d_in[12];
    const float* b_3  = (const float*)d_in[13];
    const float* W3   = (const float*)d_in[14];            // [500,200]
    const float* bias3= (const float*)d_in[15];
    const float* a1_4 = (const float*)d_in[16];
    const float* a2_4 = (const float*)d_in[17];
    const float* b_4  = (const float*)d_in[18];
    const float* W4   = (const float*)d_in[19];            // [300,500]
    const float* bias4= (const float*)d_in[20];

    const int B = 64, T = 300;

    // Workspace (13.44M floats): c1 [B,T,500]=9.6M, c2 [B,T,200]=3.84M.
    // Stage 4 reuse (c1/c2 dead then): spk4 = ws[0..5.76M),
    // flt4 = ws[5.76M..11.52M).
    float* ws = (float*)d_ws;
    float* c1 = ws;
    float* c2 = ws + 9600000;
    float* spk4 = ws;
    float* flt4 = ws + 5760000;

    // d_out: region1 [0..5.76M) = Wt1..4 + masks (scratch), later final s4
    // [B,300,T]; region2 [5.76M..11.52M) = L4 currents, later final filt.
    float* out = (float*)d_out;
    float* reg1 = out;
    float* reg2 = out + 5760000;
    float* Wt1 = reg1;              // [300,500] = 150000
    float* Wt2 = reg1 + 150000;     // [500,200] = 100000
    float* Wt3 = reg1 + 250000;     // [200,500] = 100000
    float* Wt4 = reg1 + 350000;     // [500,300] = 150000
    // masks (u32), 8B-aligned, all dead before transpose_out2 writes reg1:
    unsigned* m0 = (unsigned*)(reg1 + 500000);   // [64,300,10] = 192000
    unsigned* m1 = (unsigned*)(reg1 + 692000);   // [64,300,16] = 307200
    unsigned* m2 = (unsigned*)(reg1 + 999200);   // [64,300, 8] = 153600
    unsigned* m3 = (unsigned*)(reg1 + 1152800);  // [64,300,16] = 307200

    const dim3 tb(32, 8);

    // Weight transposes (fused) + input transpose-pack
    transpose_w4<<<dim3(16, 16, 4), tb, 0, stream>>>(W1, Wt1, W2, Wt2,
                                                     W3, Wt3, W4, Wt4);
    transpose_pack<<<dim3(10, 10, B), tb, 0, stream>>>(inputs, m0, 300, 300, 10);

    // Layer 1: 300 -> 500   (OPL=4: 2 o-blocks of 256)
    spmm_snn<4, 32><<<dim3(2, 10, B), 256, 0, stream>>>(m0, Wt1, c1, 300, 500, T, 10);
    lif_pack<<<dim3(8, B), 64, 0, stream>>>(c1, m1, bias1, a1_1, a2_1, b_1, 500, 16);
    // Layer 2: 500 -> 200   (OPL=2, KG=64: 8 chunk iters)
    spmm_snn<2, 64><<<dim3(2, 10, B), 256, 0, stream>>>(m1, Wt2, c2, 500, 200, T, 16);
    lif_pack<<<dim3(4, B), 64, 0, stream>>>(c2, m2, bias2, a1_2, a2_2, b_2, 200, 8);
    // Layer 3: 200 -> 500   (OPL=4)
    spmm_snn<4, 32><<<dim3(2, 10, B), 256, 0, stream>>>(m2, Wt3, c1, 200, 500, T, 8);
    lif_pack<<<dim3(8, B), 64, 0, stream>>>(c1, m3, bias3, a1_3, a2_3, b_3, 500, 16);
    // Layer 4: 500 -> 300   (OPL=2, KG=64), currents into reg2
    spmm_snn<2, 64><<<dim3(3, 10, B), 256, 0, stream>>>(m3, Wt4, reg2, 500, 300, T, 16);
    // LIF+filter: spikes -> spk4 (ws), filt -> flt4 (ws); c1/c2 dead.
    lif4_t<<<dim3(5, B), 64, 0, stream>>>(reg2, spk4, flt4, bias4, a1_4, a2_4, b_4, 300);

    // Fused final transposes [B,T,300] -> [B,300,T]: s4 -> reg1, filt -> reg2.
    transpose_out2<<<dim3(10, 10, 128), tb, 0, stream>>>(spk4, flt4, reg1, reg2);
}

// Round 8
// 461.140 us; speedup vs baseline: 1.0550x; 1.0550x over previous
//
#include <hip/hip_runtime.h>

// ---- filter / neuron constants (double, matching the Python reference) ----
#define EMD 0.8824969025845955      // exp(-1/8)
#define ESD 0.6065306597126334      // exp(-1/2)
#define A1C ((float)(EMD + ESD))                    // y[t-1] coeff
#define A2C ((float)(-(EMD * ESD)))                 // y[t-2] coeff
#define BC  ((float)((8.0 / 6.0) * (EMD - ESD)))    // x[t] coeff (ETA=8/6)
#define EMF ((float)EMD)                            // reset decay

// B=64, T=300. Layers: 300 -> 500 -> 200 -> 500 -> 300.
//
// Exactness contract (absmax 0.0 through r12): reference currents are a
// SEQUENTIAL ascending-i fp32 fold of W[o,i]*s[i]; spikes are exactly 0/1.
// Skipping s==0 terms is bitwise-neutral; set bits processed ascending is
// the SAME add sequence. Spikes travel as packed u32 masks (bit j of word w
// = neuron w*32+j); walk = ascending bits within word, words/chunks
// ascending -> identical fold per (t,o).
//
// History: r6 (VALU bit-extract) loses: >1 VALU op per accumulated float.
// r7 (dense reg fmac) 8x: spill + dense floor >= sparse measured. r8 (16KB
// LDS, reg staging, prefetch) 77us. r9 (s_load masks) regressed: SMEM shares
// lgkmcnt with DS out-of-order. r10 (global_load_lds; fusing transpose INTO
// 1-wave/CU scan) regressed both. r11 (r8 staging + vmcnt mask loads +
// prefetch-16 scans) 475us, spmm 80us occ 41%. r12 (OPL=4 32KB, KG=64 for
// L2/L4) 486us: OPL=4 got 75.5us but occ 24% (grid == 5-block LDS cap, no
// queue slack); KG=64 halved L2/L4 occupancy for nothing. r13: OPL=4 keeps
// visits halved AND doubles queued blocks (TCN 16, grid 2x19x64); L2/L4
// revert to r11's OPL=2/16KB config; u32 words everywhere.

// ---------------------------------------------------------------------------
// Fused weight transposes: z selects one of 4 W[O,K] -> Wt[K,O] jobs.
// ---------------------------------------------------------------------------
__global__ __launch_bounds__(256) void transpose_w4(
    const float* __restrict__ W1, float* __restrict__ D1,
    const float* __restrict__ W2, float* __restrict__ D2,
    const float* __restrict__ W3, float* __restrict__ D3,
    const float* __restrict__ W4, float* __restrict__ D4)
{
    __shared__ float tile[32][33];
    int R, C; const float* S; float* D;
    switch (blockIdx.z) {
        case 0:  S = W1; D = D1; R = 500; C = 300; break;
        case 1:  S = W2; D = D2; R = 200; C = 500; break;
        case 2:  S = W3; D = D3; R = 500; C = 200; break;
        default: S = W4; D = D4; R = 300; C = 500; break;
    }
    const int c0 = blockIdx.x * 32;
    const int r0 = blockIdx.y * 32;
    if (c0 >= C || r0 >= R) return;       // block-uniform, before barrier
    const int tx = threadIdx.x;           // 0..31
    const int ty = threadIdx.y;           // 0..7
#pragma unroll
    for (int s = 0; s < 4; s++) {
        const int r = r0 + ty + 8 * s;
        const int c = c0 + tx;
        if (r < R && c < C) tile[ty + 8 * s][tx] = S[(size_t)r * C + c];
    }
    __syncthreads();
#pragma unroll
    for (int s = 0; s < 4; s++) {
        const int c = c0 + ty + 8 * s;
        const int r = r0 + tx;
        if (c < C && r < R) D[(size_t)c * R + r] = tile[tx][ty + 8 * s];
    }
}

// ---------------------------------------------------------------------------
// Input transpose+pack: src [B][R=K][C=T] binary floats -> masks
// M[b][t][kw] (MW u32 per row), bit j of word kw = (src[b][kw*32+j][t] != 0).
// ---------------------------------------------------------------------------
__global__ __launch_bounds__(256) void transpose_pack(
    const float* __restrict__ src, unsigned* __restrict__ M,
    int R, int C, int MW)
{
    __shared__ float tile[32][33];
    const int c0 = blockIdx.x * 32;       // t block
    const int r0 = blockIdx.y * 32;       // k block (one mask word)
    const int b  = blockIdx.z;
    const float* S = src + (size_t)b * R * C;
    const int tx = threadIdx.x;           // 0..31
    const int ty = threadIdx.y;           // 0..7
#pragma unroll
    for (int s = 0; s < 4; s++) {
        const int r = r0 + ty + 8 * s;
        const int c = c0 + tx;
        tile[ty + 8 * s][tx] = (r < R && c < C) ? S[(size_t)r * C + c] : 0.0f;
    }
    __syncthreads();
    const int wv   = ty >> 1;             // 0..3
    const int half = ty & 1;
#pragma unroll
    for (int s = 0; s < 4; s++) {
        const int tl = wv * 8 + s * 2 + half;          // 0..31, both halves
        const float v = tile[tx][tl];                  // OOB pre-zeroed
        const unsigned long long mb = __ballot(v != 0.0f);
        const int t = c0 + tl;
        if (tx == 0 && t < C) {
            const unsigned w32 = half ? (unsigned)(mb >> 32) : (unsigned)mb;
            M[((size_t)b * C + t) * MW + (r0 >> 5)] = w32;
        }
    }
}

// ---------------------------------------------------------------------------
// Sparse spike GEMM, templated:
//   OPL = outputs per lane (2 -> float2/ds_read_b64, 4 -> float4/b128)
//   NU  = t-slots per wave (t-chunk = 4*NU)
// C[b,t,o] = sum_i Wt[i,o] * bit(M[b,t,i]), skipping zeros. KG fixed at 32
// (u32 mask words; r12's KG=64 halved occupancy for no walk gain).
// Block: 256 thr (4 waves), o-chunk OCN=64*OPL, t-chunk 4*NU.
// K staged in 32-row LDS chunks, weights register-prefetched one chunk
// ahead (r8 staging). Masks: per-lane-addressed VECTOR broadcast loads
// (vmcnt, not s_load/lgkmcnt); readfirstlane at walk time. Walk: scalar ctz
// on wave-uniform words, 4/2/1-wide groups, OPL adds per set-bit visit.
//   L1/L3 (O=500): <4,4> -> visits halved (vs OPL=2) AND grid 2x19x64=2432
//     blocks ~= 9.5 queued/CU against the 5-block LDS cap (r12 had 5/5:
//     zero queue slack -> occ 24%).
//   L2/L4: <2,8> -> r11's proven 16KB config (occ 41%).
// ---------------------------------------------------------------------------
template<int OPL> struct VecSel;
template<> struct VecSel<2> { using T = float2; };
template<> struct VecSel<4> { using T = float4; };

__device__ __forceinline__ void vzero(float2& a){ a.x=0.f; a.y=0.f; }
__device__ __forceinline__ void vzero(float4& a){ a.x=0.f; a.y=0.f; a.z=0.f; a.w=0.f; }
__device__ __forceinline__ void vaccum(float2& a, const float2 w){ a.x+=w.x; a.y+=w.y; }
__device__ __forceinline__ void vaccum(float4& a, const float4 w){ a.x+=w.x; a.y+=w.y; a.z+=w.z; a.w+=w.w; }

// walk one wave-uniform u32 mask word into one OPL-wide accumulator
#define WALK32(mw, accu, wl)                                                  \
    {                                                                         \
        unsigned mask_ = (mw);                                                \
        int n_ = __popc(mask_);                                               \
        while (n_ >= 4) {                                                     \
            const int j0_ = __builtin_ctz(mask_); mask_ &= mask_ - 1u;        \
            const int j1_ = __builtin_ctz(mask_); mask_ &= mask_ - 1u;        \
            const int j2_ = __builtin_ctz(mask_); mask_ &= mask_ - 1u;        \
            const int j3_ = __builtin_ctz(mask_); mask_ &= mask_ - 1u;        \
            const VT w0_ = *(const VT*)(&(wl)[j0_ * OCN]);                    \
            const VT w1_ = *(const VT*)(&(wl)[j1_ * OCN]);                    \
            const VT w2_ = *(const VT*)(&(wl)[j2_ * OCN]);                    \
            const VT w3_ = *(const VT*)(&(wl)[j3_ * OCN]);                    \
            vaccum(accu, w0_); vaccum(accu, w1_);                             \
            vaccum(accu, w2_); vaccum(accu, w3_);                             \
            n_ -= 4;                                                          \
        }                                                                     \
        if (n_ >= 2) {                                                        \
            const int j0_ = __builtin_ctz(mask_); mask_ &= mask_ - 1u;        \
            const int j1_ = __builtin_ctz(mask_); mask_ &= mask_ - 1u;        \
            const VT w0_ = *(const VT*)(&(wl)[j0_ * OCN]);                    \
            const VT w1_ = *(const VT*)(&(wl)[j1_ * OCN]);                    \
            vaccum(accu, w0_); vaccum(accu, w1_);                             \
            n_ -= 2;                                                          \
        }                                                                     \
        if (n_ > 0) {                                                         \
            const int j0_ = __builtin_ctz(mask_);                             \
            const VT w0_ = *(const VT*)(&(wl)[j0_ * OCN]);                    \
            vaccum(accu, w0_);                                                \
        }                                                                     \
    }

template<int OPL, int NU>
__global__ __launch_bounds__(256) void spmm_snn(
    const unsigned* __restrict__ M, const float* __restrict__ Wt,
    float* __restrict__ C, int K, int O, int T, int MW)
{
    constexpr int OCN = OPL * 64;
    constexpr int KG  = 32;
    constexpr int C4  = OCN / 4;          // float4 columns per row
    constexpr int NF4 = KG * OCN / 1024;  // float4s per thread per chunk
    using VT = typename VecSel<OPL>::T;
    __shared__ float Wls[KG * OCN];       // OPL=2: 16KB, OPL=4: 32KB
    const int tid  = threadIdx.x;
    const int lane = tid & 63;
    const int wv   = tid >> 6;            // 0..3 (per-lane -> vector loads)
    const int oc   = blockIdx.x * OCN;
    const int t0   = blockIdx.y * (NU * 4);
    const int b    = blockIdx.z;

    const unsigned* Mb = M + (size_t)b * T * MW;
    float* Cb = C + (size_t)b * T * O;

    VT acc[NU];
#pragma unroll
    for (int u = 0; u < NU; u++) vzero(acc[u]);

    const int nkc = (K + KG - 1) / KG;
    float4 wpf[NF4];

#define LOADW(kc)                                                              \
    {                                                                          \
        const int kb_ = (kc) * KG;                                             \
        _Pragma("unroll")                                                      \
        for (int r = 0; r < NF4; r++) {                                        \
            const int idx = r * 256 + tid;                                     \
            const int k = kb_ + idx / C4;                                      \
            const int o = oc + (idx % C4) * 4;                                 \
            float4 w = make_float4(0.f, 0.f, 0.f, 0.f);                        \
            if (k < K && o + 3 < O)                                            \
                w = *reinterpret_cast<const float4*>(&Wt[(size_t)k * O + o]);  \
            wpf[r] = w;                                                        \
        }                                                                      \
    }

#define STOREW()                                                               \
    {                                                                          \
        _Pragma("unroll")                                                      \
        for (int r = 0; r < NF4; r++) {                                        \
            const int idx = r * 256 + tid;                                     \
            *reinterpret_cast<float4*>(                                        \
                &Wls[(idx / C4) * OCN + (idx % C4) * 4]) = wpf[r];             \
        }                                                                      \
    }

    // mask rows: per-lane (tid-derived) addresses -> VECTOR broadcast loads
    // on vmcnt. readfirstlane only at walk time. Invalid t clamps to row 0,
    // value masked to 0.
    const unsigned* mrow[NU];
    bool tvalid[NU];
#pragma unroll
    for (int u = 0; u < NU; u++) {
        const int t = t0 + u * 4 + wv;
        tvalid[u] = (t < T);
        mrow[u] = Mb + (size_t)(tvalid[u] ? t : 0) * MW;
    }

    unsigned mk[NU], mkn[NU];
#define LOADM(kc, dst)                                                         \
    {                                                                          \
        _Pragma("unroll")                                                      \
        for (int u = 0; u < NU; u++)                                           \
            dst[u] = tvalid[u] ? mrow[u][(kc)] : 0u;                           \
    }

    LOADW(0)
    LOADM(0, mk)
    STOREW()
    __syncthreads();

    // per-lane LDS base: row j's VT for this lane at float offset j*OCN
    const float* wl = &Wls[lane * OPL];

    for (int kc = 0; kc < nkc; kc++) {
        if (kc + 1 < nkc) {
            LOADW(kc + 1)          // global->reg, lands during the walk
            LOADM(kc + 1, mkn)
        }

#pragma unroll
        for (int u = 0; u < NU; u++) {
            const unsigned m_ = (unsigned)__builtin_amdgcn_readfirstlane(mk[u]);
            WALK32(m_, acc[u], wl)             // t = t0 + u*4 + wv
        }

        if (kc + 1 < nkc) {
            __syncthreads();       // all waves done reading Wls
            STOREW()
#pragma unroll
            for (int u = 0; u < NU; u++) mk[u] = mkn[u];
            __syncthreads();       // Wls chunk kc+1 visible
        }
    }

#pragma unroll
    for (int u = 0; u < NU; u++) {
        const int t = t0 + u * 4 + wv;
        const int o = oc + lane * OPL;
        if (t < T && o + OPL - 1 < O)         // O mult of OPL -> all-or-nothing
            *reinterpret_cast<VT*>(&Cb[(size_t)t * O + o]) = acc[u];
    }
#undef LOADW
#undef STOREW
#undef LOADM
}

// ---------------------------------------------------------------------------
// LIF (layers 1-3): currents C[b,t,o] -> packed spike masks M[b][t][MW].
// One wave per (b, 64-o-chunk); per t: LIF step + __ballot -> one 8B store.
// Prefetch ring depth 16: ~1 wave/SIMD, ILP is the only latency cover.
// ---------------------------------------------------------------------------
#define LIF_STEP_S(xval, sval)                                                 \
    {                                                                          \
        const float y = A1 * y1 + A2 * y2 + Bc * (xval); y2 = y1; y1 = y;      \
        const float v = y + bi + r;                                            \
        sval = (v >= 1.0f) ? 1.0f : 0.0f;                                      \
        r = r * EMF - sval;                                                    \
    }

__global__ __launch_bounds__(64) void lif_pack(
    const float* __restrict__ C, unsigned* __restrict__ M,
    const float* __restrict__ bias,
    const float* __restrict__ a1p, const float* __restrict__ a2p,
    const float* __restrict__ bp, int O, int MW)
{
    const int lane = threadIdx.x;
    const int o = blockIdx.x * 64 + lane;
    const int b = blockIdx.y;
    if (o >= O) return;                    // exited lanes ballot as 0
    const float A1 = a1p[0], A2 = a2p[0], Bc = bp[0];
    const float bi = bias[o];
    const float* col = C + (size_t)b * 300 * O + o;
    unsigned long long* Mp =
        (unsigned long long*)(M + (size_t)b * 300 * MW);
    const int pair = blockIdx.x;
    const int hw   = MW >> 1;

    float pf[16];
#pragma unroll
    for (int u = 0; u < 16; u++) pf[u] = col[(size_t)u * O];

    float y1 = 0.f, y2 = 0.f, r = 0.f;
    for (int blk = 0; blk < 18; blk++) {       // t = 0..287
#pragma unroll
        for (int u = 0; u < 16; u++) {
            const int t = blk * 16 + u;
            const float x = pf[u];
            if (t + 16 < 300) pf[u] = col[(size_t)(t + 16) * O];
            float s;
            LIF_STEP_S(x, s)
            const unsigned long long mb = __ballot(s != 0.0f);
            if (lane == 0) Mp[(size_t)t * hw + pair] = mb;
        }
    }
#pragma unroll
    for (int u = 0; u < 12; u++) {             // t = 288..299
        const float x = pf[u];
        float s;
        LIF_STEP_S(x, s)
        const unsigned long long mb = __ballot(s != 0.0f);
        if (lane == 0) Mp[(size_t)(288 + u) * hw + pair] = mb;
    }
}

// ---------------------------------------------------------------------------
// Layer-4 LIF + fixed output dual-exp IIR. Cc: currents (read-only),
// S4: spikes out, F: filtered out, all [B,T,300]. Prefetch ring depth 16.
// ---------------------------------------------------------------------------
__global__ __launch_bounds__(64) void lif4_t(
    const float* __restrict__ Cc, float* __restrict__ S4,
    float* __restrict__ F, const float* __restrict__ bias,
    const float* __restrict__ a1p, const float* __restrict__ a2p,
    const float* __restrict__ bp, int O)
{
    const int o = blockIdx.x * 64 + threadIdx.x;
    const int b = blockIdx.y;
    if (o >= O) return;
    const float A1 = a1p[0], A2 = a2p[0], Bc = bp[0];
    const float bi = bias[o];
    const float* col = Cc + (size_t)b * 300 * O + o;
    float* scol = S4 + (size_t)b * 300 * O + o;
    float* fcol = F  + (size_t)b * 300 * O + o;

    float pf[16];
#pragma unroll
    for (int u = 0; u < 16; u++) pf[u] = col[(size_t)u * O];

    float y1 = 0.f, y2 = 0.f, r = 0.f;
    float z1 = 0.f, z2 = 0.f;
    for (int blk = 0; blk < 18; blk++) {       // t = 0..287
#pragma unroll
        for (int u = 0; u < 16; u++) {
            const int t = blk * 16 + u;
            const float x = pf[u];
            if (t + 16 < 300) pf[u] = col[(size_t)(t + 16) * O];
            float s;
            LIF_STEP_S(x, s)
            const float z = A1C * z1 + A2C * z2 + BC * s; z2 = z1; z1 = z;
            scol[(size_t)t * O] = s;
            fcol[(size_t)t * O] = z;
        }
    }
#pragma unroll
    for (int u = 0; u < 12; u++) {             // t = 288..299
        const int t = 288 + u;
        const float x = pf[u];
        float s;
        LIF_STEP_S(x, s)
        const float z = A1C * z1 + A2C * z2 + BC * s; z2 = z1; z1 = z;
        scol[(size_t)t * O] = s;
        fcol[(size_t)t * O] = z;
    }
}

// ---------------------------------------------------------------------------
// Fused final transposes: z<64 -> s4 [b][300][300]^T, z>=64 -> filt. Both
// jobs read independent ws buffers and write independent d_out regions.
// ---------------------------------------------------------------------------
__global__ __launch_bounds__(256) void transpose_out2(
    const float* __restrict__ s4, const float* __restrict__ flt,
    float* __restrict__ o1, float* __restrict__ o2)
{
    __shared__ float tile[32][33];
    const int z   = blockIdx.z;
    const int b   = z & 63;
    const int job = z >> 6;
    const float* S = (job ? flt : s4) + (size_t)b * 90000;
    float* D = (job ? o2 : o1) + (size_t)b * 90000;
    const int c0 = blockIdx.x * 32;
    const int r0 = blockIdx.y * 32;
    const int tx = threadIdx.x;
    const int ty = threadIdx.y;
#pragma unroll
    for (int s = 0; s < 4; s++) {
        const int r = r0 + ty + 8 * s;
        const int c = c0 + tx;
        if (r < 300 && c < 300) tile[ty + 8 * s][tx] = S[(size_t)r * 300 + c];
    }
    __syncthreads();
#pragma unroll
    for (int s = 0; s < 4; s++) {
        const int c = c0 + ty + 8 * s;
        const int r = r0 + tx;
        if (c < 300 && r < 300) D[(size_t)c * 300 + r] = tile[tx][ty + 8 * s];
    }
}

// ---------------------------------------------------------------------------
extern "C" void kernel_launch(void* const* d_in, const int* in_sizes, int n_in,
                              void* d_out, int out_size, void* d_ws, size_t ws_size,
                              hipStream_t stream)
{
    const float* inputs = (const float*)d_in[0];           // [64,300,300] binary
    const float* a1_1 = (const float*)d_in[1];
    const float* a2_1 = (const float*)d_in[2];
    const float* b_1  = (const float*)d_in[3];
    const float* W1   = (const float*)d_in[4];             // [500,300]
    const float* bias1= (const float*)d_in[5];
    const float* a1_2 = (const float*)d_in[6];
    const float* a2_2 = (const float*)d_in[7];
    const float* b_2  = (const float*)d_in[8];
    const float* W2   = (const float*)d_in[9];             // [200,500]
    const float* bias2= (const float*)d_in[10];
    const float* a1_3 = (const float*)d_in[11];
    const float* a2_3 = (const float*)d_in[12];
    const float* b_3  = (const float*)d_in[13];
    const float* W3   = (const float*)d_in[14];            // [500,200]
    const float* bias3= (const float*)d_in[15];
    const float* a1_4 = (const float*)d_in[16];
    const float* a2_4 = (const float*)d_in[17];
    const float* b_4  = (const float*)d_in[18];
    const float* W4   = (const float*)d_in[19];            // [300,500]
    const float* bias4= (const float*)d_in[20];

    const int B = 64, T = 300;

    // Workspace (13.44M floats): c1 [B,T,500]=9.6M, c2 [B,T,200]=3.84M.
    // Stage 4 reuse (c1/c2 dead then): spk4 = ws[0..5.76M),
    // flt4 = ws[5.76M..11.52M).
    float* ws = (float*)d_ws;
    float* c1 = ws;
    float* c2 = ws + 9600000;
    float* spk4 = ws;
    float* flt4 = ws + 5760000;

    // d_out: region1 [0..5.76M) = Wt1..4 + masks (scratch), later final s4
    // [B,300,T]; region2 [5.76M..11.52M) = L4 currents, later final filt.
    float* out = (float*)d_out;
    float* reg1 = out;
    float* reg2 = out + 5760000;
    float* Wt1 = reg1;              // [300,500] = 150000
    float* Wt2 = reg1 + 150000;     // [500,200] = 100000
    float* Wt3 = reg1 + 250000;     // [200,500] = 100000
    float* Wt4 = reg1 + 350000;     // [500,300] = 150000
    // masks (u32), 8B-aligned, all dead before transpose_out2 writes reg1:
    unsigned* m0 = (unsigned*)(reg1 + 500000);   // [64,300,10] = 192000
    unsigned* m1 = (unsigned*)(reg1 + 692000);   // [64,300,16] = 307200
    unsigned* m2 = (unsigned*)(reg1 + 999200);   // [64,300, 8] = 153600
    unsigned* m3 = (unsigned*)(reg1 + 1152800);  // [64,300,16] = 307200

    const dim3 tb(32, 8);

    // Weight transposes (fused) + input transpose-pack
    transpose_w4<<<dim3(16, 16, 4), tb, 0, stream>>>(W1, Wt1, W2, Wt2,
                                                     W3, Wt3, W4, Wt4);
    transpose_pack<<<dim3(10, 10, B), tb, 0, stream>>>(inputs, m0, 300, 300, 10);

    // Layer 1: 300 -> 500   (OPL=4, TCN=16: 2432 blocks vs 5-block LDS cap)
    spmm_snn<4, 4><<<dim3(2, 19, B), 256, 0, stream>>>(m0, Wt1, c1, 300, 500, T, 10);
    lif_pack<<<dim3(8, B), 64, 0, stream>>>(c1, m1, bias1, a1_1, a2_1, b_1, 500, 16);
    // Layer 2: 500 -> 200   (r11 proven config: OPL=2, 16KB)
    spmm_snn<2, 8><<<dim3(2, 10, B), 256, 0, stream>>>(m1, Wt2, c2, 500, 200, T, 16);
    lif_pack<<<dim3(4, B), 64, 0, stream>>>(c2, m2, bias2, a1_2, a2_2, b_2, 200, 8);
    // Layer 3: 200 -> 500   (OPL=4, TCN=16)
    spmm_snn<4, 4><<<dim3(2, 19, B), 256, 0, stream>>>(m2, Wt3, c1, 200, 500, T, 8);
    lif_pack<<<dim3(8, B), 64, 0, stream>>>(c1, m3, bias3, a1_3, a2_3, b_3, 500, 16);
    // Layer 4: 500 -> 300   (OPL=2, 16KB), currents into reg2
    spmm_snn<2, 8><<<dim3(3, 10, B), 256, 0, stream>>>(m3, Wt4, reg2, 500, 300, T, 16);
    // LIF+filter: spikes -> spk4 (ws), filt -> flt4 (ws); c1/c2 dead.
    lif4_t<<<dim3(5, B), 64, 0, stream>>>(reg2, spk4, flt4, bias4, a1_4, a2_4, b_4, 300);

    // Fused final transposes [B,T,300] -> [B,300,T]: s4 -> reg1, filt -> reg2.
    transpose_out2<<<dim3(10, 10, 128), tb, 0, stream>>>(spk4, flt4, reg1, reg2);
}